// Round 3
// baseline (783.650 us; speedup 1.0000x reference)
//
#include <hip/hip_runtime.h>

// ---- problem constants ----
constexpr int B_  = 128;
constexpr int T_  = 24;
constexpr int E_  = 512;
constexpr int H_  = 512;
constexpr int V_  = 10000;
constexpr int G4  = 2048;   // 4*H
constexpr int TP1 = 25;     // T+1
constexpr int VP  = 10112;  // V padded to 79*128 for tiled B reads

typedef __attribute__((ext_vector_type(8))) short bf16x8;   // 8 bf16 = 4 VGPR
typedef __attribute__((ext_vector_type(4))) short short4v;  // 4 bf16 = 8 B
typedef __attribute__((ext_vector_type(4))) float f32x4;

#define MFMA_16x16x32_BF16(a, b, c) __builtin_amdgcn_mfma_f32_16x16x32_bf16((a), (b), (c), 0, 0, 0)

// fp32 -> bf16 round-to-nearest-even (bit-level, no header ABI dependence)
__device__ inline unsigned short f2bf(float f) {
    unsigned int u = __float_as_uint(f);
    unsigned int r = (u + 0x7FFFu + ((u >> 16) & 1u)) >> 16;
    return (unsigned short)r;
}

// async global->LDS, 16B per lane. LDS dest must be linear-in-lane (it is:
// we pass per-lane ptrs equal to wave_base + lane*16).
__device__ inline void gl16(const unsigned short* g, unsigned short* l) {
    __builtin_amdgcn_global_load_lds(
        (const __attribute__((address_space(1))) unsigned int*)g,
        (__attribute__((address_space(3))) unsigned int*)l, 16, 0, 0);
}

// ---------------------------------------------------------------------------
// Bulk fp32 -> bf16 convert (float4 in, short4 out). n4 = elem_count/4.
// ---------------------------------------------------------------------------
__global__ __launch_bounds__(256) void k_cvt(const float* __restrict__ src,
                                             unsigned short* __restrict__ dst, int n4) {
    int i = blockIdx.x * 256 + threadIdx.x;
    if (i >= n4) return;
    float4 v = ((const float4*)src)[i];
    short4v o;
    o[0] = (short)f2bf(v.x); o[1] = (short)f2bf(v.y);
    o[2] = (short)f2bf(v.z); o[3] = (short)f2bf(v.w);
    ((short4v*)dst)[i] = o;
}

// ---------------------------------------------------------------------------
// Embedding gather -> bf16, padding_idx(0) -> zeros. Also re-inits the grid
// barrier state for the persistent LSTM kernel (every launch / graph replay).
// ---------------------------------------------------------------------------
__global__ __launch_bounds__(256) void k_embed(const float* __restrict__ Wemb,
                                               const int* __restrict__ captions,
                                               unsigned short* __restrict__ Xemb,
                                               unsigned* __restrict__ bar) {
    if (blockIdx.x == 0 && threadIdx.x == 0) { bar[0] = 0u; bar[1] = 0u; }
    int i = blockIdx.x * 256 + threadIdx.x;     // one thread per 4 elems
    if (i >= 3072 * 128) return;
    int row = i >> 7;                           // m = t*128 + b
    int k4  = i & 127;
    int b = row & 127, t = row >> 7;
    int tok = captions[b * T_ + t];
    short4v o = {0, 0, 0, 0};
    if (tok > 0 && tok < V_) {                  // tok==0 is padding -> zeros
        float4 v = ((const float4*)(Wemb + (long)tok * E_))[k4];
        o[0] = (short)f2bf(v.x); o[1] = (short)f2bf(v.y);
        o[2] = (short)f2bf(v.z); o[3] = (short)f2bf(v.w);
    }
    ((short4v*)Xemb)[(long)row * 128 + k4] = o;
}

// ---------------------------------------------------------------------------
// t=0 one-hot row (only!) + (captions_length - 1) tail. Rows t>=1 are fully
// written by k_logits, so zero-filling them here would be wasted bandwidth.
// ---------------------------------------------------------------------------
__global__ __launch_bounds__(256) void k_start(float* __restrict__ out,
                                               const int* __restrict__ cap_len) {
    int idx = blockIdx.x * 256 + threadIdx.x;
    constexpr int Q = V_ / 4;                    // 2500 float4 per row
    if (idx < B_ * Q) {
        int b = idx / Q;
        int q = idx - b * Q;
        float4 zero = {0.f, 0.f, 0.f, 0.f};
        float4 one1 = {0.f, 1.f, 0.f, 0.f};      // one-hot at v=1
        ((float4*)out)[(long)b * (TP1 * Q) + q] = (q == 0) ? one1 : zero;
    }
    if (idx < B_) {
        out[(size_t)B_ * TP1 * V_ + idx] = (float)(cap_len[idx] - 1);
    }
}

// ---------------------------------------------------------------------------
// Precompute P[m][n] = Xemb[m] . Wih[n] + bih[n] + bhh[n]   (fp32 out)
// M=3072 (48 tiles of 64), N=2048 (32 tiles of 64), K=512. XCD-swizzled.
// ---------------------------------------------------------------------------
__global__ __launch_bounds__(256) void k_pregemm(const unsigned short* __restrict__ Xemb,
                                                 const unsigned short* __restrict__ Wih,
                                                 const float* __restrict__ bih,
                                                 const float* __restrict__ bhh,
                                                 float* __restrict__ P) {
    int bid = blockIdx.x;                       // 0..383
    int w   = threadIdx.x >> 6;
    int xcd = bid & 7;
    int q   = (bid >> 3) * 4 + w;               // 0..191 within-XCD wave index
    int MI  = q % 48;
    int NI  = xcd * 4 + q / 48;                 // 0..31
    int lane = threadIdx.x & 63;
    int lm = lane & 15, lq = lane >> 4;

    const short* As = (const short*)Xemb;
    const short* Bs = (const short*)Wih;

    f32x4 acc[4][4] = {};
    for (int k0 = 0; k0 < 512; k0 += 32) {
        int ko = k0 + lq * 8;
        bf16x8 af[4], bfr[4];
        #pragma unroll
        for (int mi = 0; mi < 4; mi++)
            af[mi] = *(const bf16x8*)(As + (long)(MI * 64 + mi * 16 + lm) * 512 + ko);
        #pragma unroll
        for (int ni = 0; ni < 4; ni++)
            bfr[ni] = *(const bf16x8*)(Bs + (long)(NI * 64 + ni * 16 + lm) * 512 + ko);
        #pragma unroll
        for (int mi = 0; mi < 4; mi++)
            #pragma unroll
            for (int ni = 0; ni < 4; ni++)
                acc[mi][ni] = MFMA_16x16x32_BF16(af[mi], bfr[ni], acc[mi][ni]);
    }

    float bias[4];
    #pragma unroll
    for (int ni = 0; ni < 4; ni++) {
        int n = NI * 64 + ni * 16 + lm;
        bias[ni] = bih[n] + bhh[n];
    }

    #pragma unroll
    for (int mi = 0; mi < 4; mi++) {
        #pragma unroll
        for (int r = 0; r < 4; r++) {
            int m = MI * 64 + mi * 16 + lq * 4 + r;
            #pragma unroll
            for (int ni = 0; ni < 4; ni++) {
                int n = NI * 64 + ni * 16 + lm;
                P[(long)m * G4 + n] = acc[mi][ni][r] + bias[ni];
            }
        }
    }
}

// ---------------------------------------------------------------------------
// Persistent LSTM recurrence: 256 blocks (1/CU, co-resident by capacity),
// block = (MI 0..7, HG 0..31); 4 waves, wave w owns K-slice [w*128, +128).
// W_hh fragments loaded ONCE from fp32 into registers (64 VGPR), reused for
// all 24 steps. c lives in registers (wave w handles cell row r==w).
// One device-scope grid barrier per step; h double-buffered in global.
// ---------------------------------------------------------------------------
__global__ __launch_bounds__(256, 1) void k_lstm(const float* __restrict__ P,
                                                 const float* __restrict__ Whh,
                                                 unsigned short* __restrict__ h0,
                                                 unsigned short* __restrict__ h1,
                                                 unsigned short* __restrict__ Hall,
                                                 unsigned* __restrict__ bar) {
    __shared__ float part[16][4][64];            // [g*4+r][wave][lane]
    int w    = threadIdx.x >> 6;                 // 0..3 (K-slice / cell row)
    int lane = threadIdx.x & 63;
    int lm = lane & 15, lq = lane >> 4;
    int MI = blockIdx.x >> 5;                    // 0..7
    int HG = blockIdx.x & 31;                    // 0..31
    int hcol = HG * 16 + lm;
    int ks = w * 128;
    int brow = MI * 16 + lq * 4 + w;             // this lane's cell row (b)

    // resident B fragments: Whh rows g*512+hcol, k-slice ks.. (fp32 -> bf16)
    bf16x8 bw[4][4];                             // [gate][kk]
    #pragma unroll
    for (int g = 0; g < 4; g++) {
        #pragma unroll
        for (int kk = 0; kk < 4; kk++) {
            const float* p = Whh + (size_t)(g * 512 + hcol) * 512 + ks + kk * 32 + lq * 8;
            float4 u = ((const float4*)p)[0];
            float4 v = ((const float4*)p)[1];
            bf16x8 f;
            f[0] = (short)f2bf(u.x); f[1] = (short)f2bf(u.y);
            f[2] = (short)f2bf(u.z); f[3] = (short)f2bf(u.w);
            f[4] = (short)f2bf(v.x); f[5] = (short)f2bf(v.y);
            f[6] = (short)f2bf(v.z); f[7] = (short)f2bf(v.w);
            bw[g][kk] = f;
        }
    }

    float cp = 0.f;                              // c[brow][hcol], in-register

    for (int t = 0; t < T_; t++) {
        const unsigned short* hin = (t & 1) ? h1 : h0;
        unsigned short* hout      = (t & 1) ? h0 : h1;

        // A fragments (h rows MI*16+lm, this wave's K-slice)
        const unsigned short* A = hin + (size_t)(MI * 16 + lm) * 512 + ks;
        bf16x8 a0 = *(const bf16x8*)(A + 0 * 32 + lq * 8);
        bf16x8 a1 = *(const bf16x8*)(A + 1 * 32 + lq * 8);
        bf16x8 a2 = *(const bf16x8*)(A + 2 * 32 + lq * 8);
        bf16x8 a3 = *(const bf16x8*)(A + 3 * 32 + lq * 8);

        // P (xW + bias) for this wave's cell row
        const float* Pt = P + (size_t)t * B_ * G4 + (size_t)brow * G4;
        float pv0 = Pt[0 * 512 + hcol];
        float pv1 = Pt[1 * 512 + hcol];
        float pv2 = Pt[2 * 512 + hcol];
        float pv3 = Pt[3 * 512 + hcol];

        f32x4 acc[4] = {};
        #pragma unroll
        for (int g = 0; g < 4; g++) {
            acc[g] = MFMA_16x16x32_BF16(a0, bw[g][0], acc[g]);
            acc[g] = MFMA_16x16x32_BF16(a1, bw[g][1], acc[g]);
            acc[g] = MFMA_16x16x32_BF16(a2, bw[g][2], acc[g]);
            acc[g] = MFMA_16x16x32_BF16(a3, bw[g][3], acc[g]);
        }

        #pragma unroll
        for (int g = 0; g < 4; g++)
            #pragma unroll
            for (int r = 0; r < 4; r++)
                part[g * 4 + r][w][lane] = acc[g][r];
        __syncthreads();

        // wave w reduces + does the cell for r == w (K-order: w'=0,1,2,3)
        float gi = part[0*4+w][0][lane] + part[0*4+w][1][lane] + part[0*4+w][2][lane] + part[0*4+w][3][lane] + pv0;
        float gf = part[1*4+w][0][lane] + part[1*4+w][1][lane] + part[1*4+w][2][lane] + part[1*4+w][3][lane] + pv1;
        float gg = part[2*4+w][0][lane] + part[2*4+w][1][lane] + part[2*4+w][2][lane] + part[2*4+w][3][lane] + pv2;
        float go = part[3*4+w][0][lane] + part[3*4+w][1][lane] + part[3*4+w][2][lane] + part[3*4+w][3][lane] + pv3;
        float si = 1.f / (1.f + expf(-gi));
        float sf = 1.f / (1.f + expf(-gf));
        float so = 1.f / (1.f + expf(-go));
        float cn = sf * cp + si * tanhf(gg);
        float hn = so * tanhf(cn);
        cp = cn;
        unsigned short hb = f2bf(hn);
        hout[brow * 512 + hcol] = hb;
        Hall[(size_t)t * (B_ * H_) + brow * 512 + hcol] = hb;

        if (t < T_ - 1) {
            __syncthreads();                     // all stores issued; part[] reads done
            if (threadIdx.x == 0) {
                __threadfence();                 // agent release (L2 writeback)
                unsigned prev = __hip_atomic_fetch_add(&bar[0], 1u, __ATOMIC_ACQ_REL,
                                                       __HIP_MEMORY_SCOPE_AGENT);
                if (prev == 255u) {              // last arriver
                    __hip_atomic_store(&bar[0], 0u, __ATOMIC_RELAXED, __HIP_MEMORY_SCOPE_AGENT);
                    __hip_atomic_store(&bar[1], (unsigned)(t + 1), __ATOMIC_RELEASE,
                                       __HIP_MEMORY_SCOPE_AGENT);
                } else {
                    while (__hip_atomic_load(&bar[1], __ATOMIC_RELAXED,
                                             __HIP_MEMORY_SCOPE_AGENT) < (unsigned)(t + 1))
                        __builtin_amdgcn_s_sleep(2);
                    (void)__hip_atomic_load(&bar[1], __ATOMIC_ACQUIRE, __HIP_MEMORY_SCOPE_AGENT);
                }
                __threadfence();                 // agent acquire (cache invalidate)
            }
            __syncthreads();
        }
    }
}

// ---------------------------------------------------------------------------
// Logits: Hall[3072,512](bf16) @ Wout_bf^T + b_out -> fp32 out[b][t+1][v].
// m97-style: 128x128 tile, BK=32, double-buffered LDS via global_load_lds.
// XCD swizzle: each XCD owns 3 M-tiles (A-chunk 384KB stays in its L2) and
// streams all 79 B-panels; 3 concurrent M-blocks reuse each panel via L2.
// Grid = 8 * (3*79) = 1896 blocks exactly.
// ---------------------------------------------------------------------------
__global__ __launch_bounds__(256) void k_logits(const unsigned short* __restrict__ Hall,
                                                const unsigned short* __restrict__ Wout,
                                                const float* __restrict__ bout,
                                                float* __restrict__ out) {
    __shared__ unsigned short ldsA[2][4096];     // [buf][128*32]
    __shared__ unsigned short ldsB[2][4096];
    int bid = blockIdx.x;
    int xcd = bid & 7;
    int q   = bid >> 3;                          // 0..236
    int MI  = xcd * 3 + (q % 3);                 // 0..23 (== timestep t)
    int NI  = q / 3;                             // 0..78
    int i    = threadIdx.x;
    int w = i >> 6, lane = i & 63;
    int lm = lane & 15, lq = lane >> 4;
    int wr = w >> 1, wc = w & 1;

    // staging addresses: thread i fills LDS elems [(j*256+i)*8, +8), j=0,1
    // = row j*64 + i/4, col (i&3)*8 of the [128][32] tile (linear-in-lane).
    const unsigned short* gA = Hall + (size_t)(MI * 128 + (i >> 2)) * 512 + (i & 3) * 8;
    const unsigned short* gB = Wout + (size_t)(NI * 128 + (i >> 2)) * 512 + (i & 3) * 8;
    unsigned short* lA = &ldsA[0][0] + i * 8;
    unsigned short* lB = &ldsB[0][0] + i * 8;

    auto stage = [&](int buf, int ks) {
        int go = ks * 32;
        gl16(gA + go,            lA + buf * 4096);
        gl16(gA + go + 64 * 512, lA + buf * 4096 + 2048);
        gl16(gB + go,            lB + buf * 4096);
        gl16(gB + go + 64 * 512, lB + buf * 4096 + 2048);
    };

    f32x4 acc[4][4] = {};
    stage(0, 0);
    for (int ksi = 0; ksi < 16; ksi++) {
        int cur = ksi & 1;
        if (ksi < 15) stage(cur ^ 1, ksi + 1);
        __syncthreads();                         // staging of cur complete
        bf16x8 af[4], bfr[4];
        #pragma unroll
        for (int mi = 0; mi < 4; mi++)
            af[mi] = *(const bf16x8*)&ldsA[cur][(wr * 64 + mi * 16 + lm) * 32 + lq * 8];
        #pragma unroll
        for (int ni = 0; ni < 4; ni++)
            bfr[ni] = *(const bf16x8*)&ldsB[cur][(wc * 64 + ni * 16 + lm) * 32 + lq * 8];
        #pragma unroll
        for (int mi = 0; mi < 4; mi++)
            #pragma unroll
            for (int ni = 0; ni < 4; ni++)
                acc[mi][ni] = MFMA_16x16x32_BF16(af[mi], bfr[ni], acc[mi][ni]);
        __syncthreads();                         // done reading cur
    }

    // epilogue: rows of this M-tile are exactly (t = MI, b = 0..127)
    #pragma unroll
    for (int mi = 0; mi < 4; mi++) {
        #pragma unroll
        for (int r = 0; r < 4; r++) {
            int b = wr * 64 + mi * 16 + lq * 4 + r;
            float* orow = out + ((size_t)b * TP1 + MI + 1) * V_;
            #pragma unroll
            for (int ni = 0; ni < 4; ni++) {
                int n = NI * 128 + wc * 64 + ni * 16 + lm;
                if (n < V_) orow[n] = acc[mi][ni][r] + bout[n];
            }
        }
    }
}

// ---------------------------------------------------------------------------
extern "C" void kernel_launch(void* const* d_in, const int* in_sizes, int n_in,
                              void* d_out, int out_size, void* d_ws, size_t ws_size,
                              hipStream_t stream) {
    const float* images   = (const float*)d_in[0];
    const int*   captions = (const int*)d_in[1];
    const int*   cap_len  = (const int*)d_in[2];
    const float* Wemb     = (const float*)d_in[3];
    const float* Wih      = (const float*)d_in[4];
    const float* Whh      = (const float*)d_in[5];
    const float* bih      = (const float*)d_in[6];
    const float* bhh      = (const float*)d_in[7];
    const float* Wout     = (const float*)d_in[8];
    const float* bout     = (const float*)d_in[9];
    float* out = (float*)d_out;

    // workspace layout (all sizes multiples of 256B)
    char* ws = (char*)d_ws;
    unsigned short* Wih_bf  = (unsigned short*)(ws);              //  2,097,152
    unsigned short* Wout_bf = (unsigned short*)(ws + 2097152);    // 10,354,688 (VP=10112 rows)
    unsigned short* Xemb    = (unsigned short*)(ws + 12451840);   //  3,145,728
    unsigned short* Hall    = (unsigned short*)(ws + 15597568);   //  3,145,728
    unsigned short* h0      = (unsigned short*)(ws + 18743296);   //    131,072
    unsigned short* h1      = (unsigned short*)(ws + 18874368);   //    131,072
    unsigned*       bar     = (unsigned*)(ws + 19005440);         //        256
    // P: 3072 x 2048 fp32 = 25,165,824. Prefer workspace; fall back to d_out
    // as scratch (safe: k_start + k_logits together rewrite every out byte
    // after the recurrence consumed P).
    constexpr size_t P_OFF   = 19005696;
    constexpr size_t WS_NEED = P_OFF + 25165824;   // 44,171,520
    float* P = (ws_size >= WS_NEED) ? (float*)(ws + P_OFF) : (float*)d_out;

    // staging
    k_cvt<<<1024, 256, 0, stream>>>(Wih,    Wih_bf,  G4 * E_ / 4);
    k_cvt<<<5000, 256, 0, stream>>>(Wout,   Wout_bf, V_ * H_ / 4);
    k_cvt<<<  64, 256, 0, stream>>>(images, h0,      B_ * H_ / 4);
    k_embed<<<1536, 256, 0, stream>>>(Wemb, captions, Xemb, bar);

    // hoisted input GEMM: P = Xemb @ Wih^T + (bih + bhh)
    k_pregemm<<<384, 256, 0, stream>>>(Xemb, Wih_bf, bih, bhh, P);

    // whole recurrence in ONE persistent kernel (Whh fp32 read directly)
    k_lstm<<<256, 256, 0, stream>>>(P, Whh, h0, h1, Hall, bar);

    // t=0 one-hot row + length tail
    k_start<<<1250, 256, 0, stream>>>(out, cap_len);

    // logits, LDS-staged 128x128 tiles
    k_logits<<<1896, 256, 0, stream>>>(Hall, Wout_bf, bout, out);
}

// Round 4
// 400.291 us; speedup vs baseline: 1.9577x; 1.9577x over previous
//
#include <hip/hip_runtime.h>

// ---- problem constants ----
constexpr int B_  = 128;
constexpr int T_  = 24;
constexpr int E_  = 512;
constexpr int H_  = 512;
constexpr int V_  = 10000;
constexpr int G4  = 2048;   // 4*H
constexpr int TP1 = 25;     // T+1
constexpr int VP  = 10112;  // V padded to 79*128 for tiled B reads

typedef __attribute__((ext_vector_type(8))) short bf16x8;   // 8 bf16 = 4 VGPR
typedef __attribute__((ext_vector_type(4))) short short4v;  // 4 bf16 = 8 B
typedef __attribute__((ext_vector_type(4))) float f32x4;

#define MFMA_16x16x32_BF16(a, b, c) __builtin_amdgcn_mfma_f32_16x16x32_bf16((a), (b), (c), 0, 0, 0)

// fp32 -> bf16 round-to-nearest-even (bit-level, no header ABI dependence)
__device__ inline unsigned short f2bf(float f) {
    unsigned int u = __float_as_uint(f);
    unsigned int r = (u + 0x7FFFu + ((u >> 16) & 1u)) >> 16;
    return (unsigned short)r;
}

// async global->LDS, 16B per lane. LDS dest must be linear-in-lane (it is:
// we pass per-lane ptrs equal to wave_base + lane*16).
__device__ inline void gl16(const unsigned short* g, unsigned short* l) {
    __builtin_amdgcn_global_load_lds(
        (const __attribute__((address_space(1))) unsigned int*)g,
        (__attribute__((address_space(3))) unsigned int*)l, 16, 0, 0);
}

// ---------------------------------------------------------------------------
// Bulk fp32 -> bf16 convert (float4 in, short4 out). n4 = elem_count/4.
// ---------------------------------------------------------------------------
__global__ __launch_bounds__(256) void k_cvt(const float* __restrict__ src,
                                             unsigned short* __restrict__ dst, int n4) {
    int i = blockIdx.x * 256 + threadIdx.x;
    if (i >= n4) return;
    float4 v = ((const float4*)src)[i];
    short4v o;
    o[0] = (short)f2bf(v.x); o[1] = (short)f2bf(v.y);
    o[2] = (short)f2bf(v.z); o[3] = (short)f2bf(v.w);
    ((short4v*)dst)[i] = o;
}

// ---------------------------------------------------------------------------
// Embedding gather -> bf16, padding_idx(0) -> zeros.
// Xemb[m][k], m = t*128 + b, 3072 rows x 512.
// ---------------------------------------------------------------------------
__global__ __launch_bounds__(256) void k_embed(const float* __restrict__ Wemb,
                                               const int* __restrict__ captions,
                                               unsigned short* __restrict__ Xemb) {
    int i = blockIdx.x * 256 + threadIdx.x;     // one thread per 4 elems
    if (i >= 3072 * 128) return;
    int row = i >> 7;                           // m = t*128 + b
    int k4  = i & 127;
    int b = row & 127, t = row >> 7;
    int tok = captions[b * T_ + t];
    short4v o = {0, 0, 0, 0};
    if (tok > 0 && tok < V_) {                  // tok==0 is padding -> zeros
        float4 v = ((const float4*)(Wemb + (long)tok * E_))[k4];
        o[0] = (short)f2bf(v.x); o[1] = (short)f2bf(v.y);
        o[2] = (short)f2bf(v.z); o[3] = (short)f2bf(v.w);
    }
    ((short4v*)Xemb)[(long)row * 128 + k4] = o;
}

// ---------------------------------------------------------------------------
// t=0 one-hot row (only!) + (captions_length - 1) tail. Rows t>=1 are fully
// written by k_logits, so zero-filling them here would be wasted bandwidth.
// ---------------------------------------------------------------------------
__global__ __launch_bounds__(256) void k_start(float* __restrict__ out,
                                               const int* __restrict__ cap_len) {
    int idx = blockIdx.x * 256 + threadIdx.x;
    constexpr int Q = V_ / 4;                    // 2500 float4 per row
    if (idx < B_ * Q) {
        int b = idx / Q;
        int q = idx - b * Q;
        float4 zero = {0.f, 0.f, 0.f, 0.f};
        float4 one1 = {0.f, 1.f, 0.f, 0.f};      // one-hot at v=1
        ((float4*)out)[(long)b * (TP1 * Q) + q] = (q == 0) ? one1 : zero;
    }
    if (idx < B_) {
        out[(size_t)B_ * TP1 * V_ + idx] = (float)(cap_len[idx] - 1);
    }
}

// ---------------------------------------------------------------------------
// Precompute P[m][n] = Xemb[m] . Wih[n] + bih[n] + bhh[n]   (fp32 out)
// M=3072 (48 tiles of 64), N=2048 (32 tiles of 64), K=512. XCD-swizzled.
// ---------------------------------------------------------------------------
__global__ __launch_bounds__(256) void k_pregemm(const unsigned short* __restrict__ Xemb,
                                                 const unsigned short* __restrict__ Wih,
                                                 const float* __restrict__ bih,
                                                 const float* __restrict__ bhh,
                                                 float* __restrict__ P) {
    int bid = blockIdx.x;                       // 0..383
    int w   = threadIdx.x >> 6;
    int xcd = bid & 7;
    int q   = (bid >> 3) * 4 + w;               // 0..191 within-XCD wave index
    int MI  = q % 48;
    int NI  = xcd * 4 + q / 48;                 // 0..31
    int lane = threadIdx.x & 63;
    int lm = lane & 15, lq = lane >> 4;

    const short* As = (const short*)Xemb;
    const short* Bs = (const short*)Wih;

    f32x4 acc[4][4] = {};
    for (int k0 = 0; k0 < 512; k0 += 32) {
        int ko = k0 + lq * 8;
        bf16x8 af[4], bfr[4];
        #pragma unroll
        for (int mi = 0; mi < 4; mi++)
            af[mi] = *(const bf16x8*)(As + (long)(MI * 64 + mi * 16 + lm) * 512 + ko);
        #pragma unroll
        for (int ni = 0; ni < 4; ni++)
            bfr[ni] = *(const bf16x8*)(Bs + (long)(NI * 64 + ni * 16 + lm) * 512 + ko);
        #pragma unroll
        for (int mi = 0; mi < 4; mi++)
            #pragma unroll
            for (int ni = 0; ni < 4; ni++)
                acc[mi][ni] = MFMA_16x16x32_BF16(af[mi], bfr[ni], acc[mi][ni]);
    }

    float bias[4];
    #pragma unroll
    for (int ni = 0; ni < 4; ni++) {
        int n = NI * 64 + ni * 16 + lm;
        bias[ni] = bih[n] + bhh[n];
    }

    #pragma unroll
    for (int mi = 0; mi < 4; mi++) {
        #pragma unroll
        for (int r = 0; r < 4; r++) {
            int m = MI * 64 + mi * 16 + lq * 4 + r;
            #pragma unroll
            for (int ni = 0; ni < 4; ni++) {
                int n = NI * 64 + ni * 16 + lm;
                P[(long)m * G4 + n] = acc[mi][ni][r] + bias[ni];
            }
        }
    }
}

// ---------------------------------------------------------------------------
// Per-step fused kernel (launch = the grid barrier; R2's in-kernel barrier
// cost 22us/step in coherence flushes — relaunch is ~4x cheaper).
// Block = (MI 0..7, HG 0..31), 4 waves; wave w owns K-slice [w*128,+128) of
// all four gate tiles. LDS reduce; wave w then does the cell for row r==w
// (cell work spread over ALL waves, unlike R1's wave-0-only tail).
// P/c prefetch issued before the MFMA chain to hide latency.
// ---------------------------------------------------------------------------
__global__ __launch_bounds__(256) void k_step(const float* __restrict__ Pt,     // P + t*128*2048
                                              const unsigned short* __restrict__ h_in,
                                              const unsigned short* __restrict__ Whh,
                                              float* __restrict__ c,
                                              unsigned short* __restrict__ h_out,
                                              unsigned short* __restrict__ Hall_t,
                                              int t) {
    __shared__ float part[16][4][64];            // [g*4+r][wave][lane]
    int w    = threadIdx.x >> 6;                 // 0..3 (K-slice / cell row)
    int lane = threadIdx.x & 63;
    int lm = lane & 15, lq = lane >> 4;
    int MI = blockIdx.x >> 5;                    // 0..7  (batch rows MI*16..+16)
    int HG = blockIdx.x & 31;                    // 0..31 (h-cols HG*16..+16)
    int hcol = HG * 16 + lm;
    int ks = w * 128;
    int brow = MI * 16 + lq * 4 + w;             // this lane's cell row (b)

    // prefetch P (xW+bias) for this wave's cell row + c_prev; latency hides
    // under the MFMA chain below.
    const float* Pr = Pt + (size_t)brow * G4;
    float pv0 = Pr[0 * 512 + hcol];
    float pv1 = Pr[1 * 512 + hcol];
    float pv2 = Pr[2 * 512 + hcol];
    float pv3 = Pr[3 * 512 + hcol];
    float cp = 0.f;
    if (t != 0) cp = c[brow * H_ + hcol];

    // K-slice GEMM
    const short* A = (const short*)h_in + (long)(MI * 16 + lm) * H_ + ks;
    const short* B0 = (const short*)Whh + (long)(0 * 512 + hcol) * H_ + ks;
    const short* B1 = (const short*)Whh + (long)(1 * 512 + hcol) * H_ + ks;
    const short* B2 = (const short*)Whh + (long)(2 * 512 + hcol) * H_ + ks;
    const short* B3 = (const short*)Whh + (long)(3 * 512 + hcol) * H_ + ks;

    f32x4 acc[4] = {};
    #pragma unroll
    for (int kk = 0; kk < 4; kk++) {
        int ko = kk * 32 + lq * 8;
        bf16x8 a = *(const bf16x8*)(A + ko);
        acc[0] = MFMA_16x16x32_BF16(a, *(const bf16x8*)(B0 + ko), acc[0]);
        acc[1] = MFMA_16x16x32_BF16(a, *(const bf16x8*)(B1 + ko), acc[1]);
        acc[2] = MFMA_16x16x32_BF16(a, *(const bf16x8*)(B2 + ko), acc[2]);
        acc[3] = MFMA_16x16x32_BF16(a, *(const bf16x8*)(B3 + ko), acc[3]);
    }

    #pragma unroll
    for (int g = 0; g < 4; g++)
        #pragma unroll
        for (int r = 0; r < 4; r++)
            part[g * 4 + r][w][lane] = acc[g][r];
    __syncthreads();

    // wave w reduces K-partials (order w'=0..3) + cell for its row
    float gi = part[0*4+w][0][lane] + part[0*4+w][1][lane] + part[0*4+w][2][lane] + part[0*4+w][3][lane] + pv0;
    float gf = part[1*4+w][0][lane] + part[1*4+w][1][lane] + part[1*4+w][2][lane] + part[1*4+w][3][lane] + pv1;
    float gg = part[2*4+w][0][lane] + part[2*4+w][1][lane] + part[2*4+w][2][lane] + part[2*4+w][3][lane] + pv2;
    float go = part[3*4+w][0][lane] + part[3*4+w][1][lane] + part[3*4+w][2][lane] + part[3*4+w][3][lane] + pv3;
    float si = 1.f / (1.f + expf(-gi));
    float sf = 1.f / (1.f + expf(-gf));
    float so = 1.f / (1.f + expf(-go));
    float cn = sf * cp + si * tanhf(gg);
    float hn = so * tanhf(cn);
    c[brow * H_ + hcol] = cn;
    unsigned short hb = f2bf(hn);
    h_out[brow * H_ + hcol] = hb;
    Hall_t[brow * H_ + hcol] = hb;
}

// ---------------------------------------------------------------------------
// Logits: Hall[3072,512](bf16) @ Wout_bf^T + b_out -> fp32 out[b][t+1][v].
// m97-style: 128x128 tile, BK=32, double-buffered LDS via global_load_lds.
// XCD swizzle: each XCD owns 3 M-tiles (A-chunk 384KB stays in its L2) and
// streams all 79 B-panels. Grid = 8 * (3*79) = 1896 blocks exactly.
// ---------------------------------------------------------------------------
__global__ __launch_bounds__(256) void k_logits(const unsigned short* __restrict__ Hall,
                                                const unsigned short* __restrict__ Wout,
                                                const float* __restrict__ bout,
                                                float* __restrict__ out) {
    __shared__ unsigned short ldsA[2][4096];     // [buf][128*32]
    __shared__ unsigned short ldsB[2][4096];
    int bid = blockIdx.x;
    int xcd = bid & 7;
    int q   = bid >> 3;                          // 0..236
    int MI  = xcd * 3 + (q % 3);                 // 0..23 (== timestep t)
    int NI  = q / 3;                             // 0..78
    int i    = threadIdx.x;
    int w = i >> 6, lane = i & 63;
    int lm = lane & 15, lq = lane >> 4;
    int wr = w >> 1, wc = w & 1;

    const unsigned short* gA = Hall + (size_t)(MI * 128 + (i >> 2)) * 512 + (i & 3) * 8;
    const unsigned short* gB = Wout + (size_t)(NI * 128 + (i >> 2)) * 512 + (i & 3) * 8;
    unsigned short* lA = &ldsA[0][0] + i * 8;
    unsigned short* lB = &ldsB[0][0] + i * 8;

    auto stage = [&](int buf, int ks) {
        int go = ks * 32;
        gl16(gA + go,            lA + buf * 4096);
        gl16(gA + go + 64 * 512, lA + buf * 4096 + 2048);
        gl16(gB + go,            lB + buf * 4096);
        gl16(gB + go + 64 * 512, lB + buf * 4096 + 2048);
    };

    f32x4 acc[4][4] = {};
    stage(0, 0);
    for (int ksi = 0; ksi < 16; ksi++) {
        int cur = ksi & 1;
        if (ksi < 15) stage(cur ^ 1, ksi + 1);
        __syncthreads();                         // staging of cur complete
        bf16x8 af[4], bfr[4];
        #pragma unroll
        for (int mi = 0; mi < 4; mi++)
            af[mi] = *(const bf16x8*)&ldsA[cur][(wr * 64 + mi * 16 + lm) * 32 + lq * 8];
        #pragma unroll
        for (int ni = 0; ni < 4; ni++)
            bfr[ni] = *(const bf16x8*)&ldsB[cur][(wc * 64 + ni * 16 + lm) * 32 + lq * 8];
        #pragma unroll
        for (int mi = 0; mi < 4; mi++)
            #pragma unroll
            for (int ni = 0; ni < 4; ni++)
                acc[mi][ni] = MFMA_16x16x32_BF16(af[mi], bfr[ni], acc[mi][ni]);
        __syncthreads();                         // done reading cur
    }

    // epilogue: rows of this M-tile are exactly (t = MI, b = 0..127)
    #pragma unroll
    for (int mi = 0; mi < 4; mi++) {
        #pragma unroll
        for (int r = 0; r < 4; r++) {
            int b = wr * 64 + mi * 16 + lq * 4 + r;
            float* orow = out + ((size_t)b * TP1 + MI + 1) * V_;
            #pragma unroll
            for (int ni = 0; ni < 4; ni++) {
                int n = NI * 128 + wc * 64 + ni * 16 + lm;
                if (n < V_) orow[n] = acc[mi][ni][r] + bout[n];
            }
        }
    }
}

// ---------------------------------------------------------------------------
extern "C" void kernel_launch(void* const* d_in, const int* in_sizes, int n_in,
                              void* d_out, int out_size, void* d_ws, size_t ws_size,
                              hipStream_t stream) {
    const float* images   = (const float*)d_in[0];
    const int*   captions = (const int*)d_in[1];
    const int*   cap_len  = (const int*)d_in[2];
    const float* Wemb     = (const float*)d_in[3];
    const float* Wih      = (const float*)d_in[4];
    const float* Whh      = (const float*)d_in[5];
    const float* bih      = (const float*)d_in[6];
    const float* bhh      = (const float*)d_in[7];
    const float* Wout     = (const float*)d_in[8];
    const float* bout     = (const float*)d_in[9];
    float* out = (float*)d_out;

    // workspace layout (all sizes multiples of 256B)
    char* ws = (char*)d_ws;
    unsigned short* Wih_bf  = (unsigned short*)(ws);              //  2,097,152
    unsigned short* Whh_bf  = (unsigned short*)(ws + 2097152);    //  2,097,152
    unsigned short* Wout_bf = (unsigned short*)(ws + 4194304);    // 10,354,688 (VP=10112 rows)
    unsigned short* Xemb    = (unsigned short*)(ws + 14548992);   //  3,145,728
    unsigned short* Hall    = (unsigned short*)(ws + 17694720);   //  3,145,728
    unsigned short* h0      = (unsigned short*)(ws + 20840448);   //    131,072
    unsigned short* h1      = (unsigned short*)(ws + 20971520);   //    131,072
    float*          cbuf    = (float*)(ws + 21102592);            //    262,144
    // P: 3072 x 2048 fp32 = 25,165,824. Prefer workspace; fall back to d_out
    // as scratch (safe: k_start + k_logits together rewrite every out byte
    // after the recurrence consumed P).
    constexpr size_t P_OFF   = 21364736;
    constexpr size_t WS_NEED = P_OFF + 25165824;   // 46,530,560
    float* P = (ws_size >= WS_NEED) ? (float*)(ws + P_OFF) : (float*)d_out;

    // staging
    k_cvt<<<1024, 256, 0, stream>>>(Wih,    Wih_bf,  G4 * E_ / 4);
    k_cvt<<<1024, 256, 0, stream>>>(Whh,    Whh_bf,  G4 * H_ / 4);
    k_cvt<<<5000, 256, 0, stream>>>(Wout,   Wout_bf, V_ * H_ / 4);
    k_cvt<<<  64, 256, 0, stream>>>(images, h0,      B_ * H_ / 4);
    k_embed<<<1536, 256, 0, stream>>>(Wemb, captions, Xemb);

    // hoisted input GEMM: P = Xemb @ Wih^T + (bih + bhh)
    k_pregemm<<<384, 256, 0, stream>>>(Xemb, Wih_bf, bih, bhh, P);

    // serial recurrence: one launch per step (launch = cheap grid barrier)
    for (int t = 0; t < T_; t++) {
        const unsigned short* hin  = (t & 1) ? h1 : h0;
        unsigned short*       hout = (t & 1) ? h0 : h1;
        k_step<<<256, 256, 0, stream>>>(P + (long)t * B_ * G4, hin, Whh_bf,
                                        cbuf, hout, Hall + (long)t * B_ * H_, t);
    }

    // t=0 one-hot row + length tail
    k_start<<<1250, 256, 0, stream>>>(out, cap_len);

    // logits, LDS-staged 128x128 tiles
    k_logits<<<1896, 256, 0, stream>>>(Hall, Wout_bf, bout, out);
}

// Round 5
// 376.668 us; speedup vs baseline: 2.0805x; 1.0627x over previous
//
#include <hip/hip_runtime.h>

// ---- problem constants ----
constexpr int B_  = 128;
constexpr int T_  = 24;
constexpr int E_  = 512;
constexpr int H_  = 512;
constexpr int V_  = 10000;
constexpr int G4  = 2048;   // 4*H
constexpr int TP1 = 25;     // T+1
constexpr int VP  = 10112;  // V padded to 79*128 for tiled B reads

typedef __attribute__((ext_vector_type(8))) short bf16x8;   // 8 bf16 = 4 VGPR
typedef __attribute__((ext_vector_type(4))) short short4v;  // 4 bf16 = 8 B
typedef __attribute__((ext_vector_type(4))) float f32x4;

#define MFMA_16x16x32_BF16(a, b, c) __builtin_amdgcn_mfma_f32_16x16x32_bf16((a), (b), (c), 0, 0, 0)

// fp32 -> bf16 round-to-nearest-even (bit-level, no header ABI dependence)
__device__ inline unsigned short f2bf(float f) {
    unsigned int u = __float_as_uint(f);
    unsigned int r = (u + 0x7FFFu + ((u >> 16) & 1u)) >> 16;
    return (unsigned short)r;
}

// async global->LDS, 16B per lane. LDS dest must be linear-in-lane.
__device__ inline void gl16(const unsigned short* g, unsigned short* l) {
    __builtin_amdgcn_global_load_lds(
        (const __attribute__((address_space(1))) unsigned int*)g,
        (__attribute__((address_space(3))) unsigned int*)l, 16, 0, 0);
}

// Bank-conflict swizzle for [128][32] bf16 tiles (row = 64 B = 4 granules of
// 16 B). Stored granule S = L ^ (row(L)&7): spreads 8 consecutive rows over
// all 8 bank-quads (2-way residual = free). Reader:
__device__ inline int swz16(int row, int lq) {      // returns short offset
    return (((row << 2) | lq) ^ (row & 7)) << 3;
}
// Writer inverse (thread i stages stored granule i of each 256-granule half):
// logical granule li = i ^ m, m = ((i>>2)&7) ^ ((i>>4)&1); chunk1 row = +64.

// ---------------------------------------------------------------------------
// All fp32 -> bf16 staging in ONE launch. Segment sizes are exact multiples
// of 256 float4s, so no bounds checks.
// ---------------------------------------------------------------------------
__global__ __launch_bounds__(256) void k_cvt_all(const float* __restrict__ Wih,
                                                 const float* __restrict__ Whh,
                                                 const float* __restrict__ Wout,
                                                 const float* __restrict__ images,
                                                 unsigned short* __restrict__ dWih,
                                                 unsigned short* __restrict__ dWhh,
                                                 unsigned short* __restrict__ dWout,
                                                 unsigned short* __restrict__ dimg) {
    int b = blockIdx.x;
    const float* src; unsigned short* dst; int i;
    if (b < 1024)      { src = Wih;    dst = dWih;  i = b * 256 + threadIdx.x; }
    else if (b < 2048) { src = Whh;    dst = dWhh;  i = (b - 1024) * 256 + threadIdx.x; }
    else if (b < 7048) { src = Wout;   dst = dWout; i = (b - 2048) * 256 + threadIdx.x; }
    else               { src = images; dst = dimg;  i = (b - 7048) * 256 + threadIdx.x; }
    float4 v = ((const float4*)src)[i];
    short4v o;
    o[0] = (short)f2bf(v.x); o[1] = (short)f2bf(v.y);
    o[2] = (short)f2bf(v.z); o[3] = (short)f2bf(v.w);
    ((short4v*)dst)[i] = o;
}

// ---------------------------------------------------------------------------
// Embedding gather -> bf16, padding_idx(0) -> zeros.
// Xemb[m][k], m = t*128 + b, 3072 rows x 512.
// ---------------------------------------------------------------------------
__global__ __launch_bounds__(256) void k_embed(const float* __restrict__ Wemb,
                                               const int* __restrict__ captions,
                                               unsigned short* __restrict__ Xemb) {
    int i = blockIdx.x * 256 + threadIdx.x;     // one thread per 4 elems
    if (i >= 3072 * 128) return;
    int row = i >> 7;                           // m = t*128 + b
    int k4  = i & 127;
    int b = row & 127, t = row >> 7;
    int tok = captions[b * T_ + t];
    short4v o = {0, 0, 0, 0};
    if (tok > 0 && tok < V_) {                  // tok==0 is padding -> zeros
        float4 v = ((const float4*)(Wemb + (long)tok * E_))[k4];
        o[0] = (short)f2bf(v.x); o[1] = (short)f2bf(v.y);
        o[2] = (short)f2bf(v.z); o[3] = (short)f2bf(v.w);
    }
    ((short4v*)Xemb)[(long)row * 128 + k4] = o;
}

// ---------------------------------------------------------------------------
// t=0 one-hot row (only!) + (captions_length - 1) tail. Rows t>=1 are fully
// written by k_logits.
// ---------------------------------------------------------------------------
__global__ __launch_bounds__(256) void k_start(float* __restrict__ out,
                                               const int* __restrict__ cap_len) {
    int idx = blockIdx.x * 256 + threadIdx.x;
    constexpr int Q = V_ / 4;                    // 2500 float4 per row
    if (idx < B_ * Q) {
        int b = idx / Q;
        int q = idx - b * Q;
        float4 zero = {0.f, 0.f, 0.f, 0.f};
        float4 one1 = {0.f, 1.f, 0.f, 0.f};      // one-hot at v=1
        ((float4*)out)[(long)b * (TP1 * Q) + q] = (q == 0) ? one1 : zero;
    }
    if (idx < B_) {
        out[(size_t)B_ * TP1 * V_ + idx] = (float)(cap_len[idx] - 1);
    }
}

// ---------------------------------------------------------------------------
// P[m][n] = Xemb[m].Wih[n] + bih[n] + bhh[n]  (fp32). M=3072, N=2048, K=512.
// 128x128 LDS-staged tiles (same structure + swizzle as k_logits).
// Grid 8*(3*16) = 384: XCD owns 3 M-tiles, streams 16 B-panels.
// ---------------------------------------------------------------------------
__global__ __launch_bounds__(256) void k_pregemm(const unsigned short* __restrict__ Xemb,
                                                 const unsigned short* __restrict__ Wih,
                                                 const float* __restrict__ bih,
                                                 const float* __restrict__ bhh,
                                                 float* __restrict__ P) {
    __shared__ unsigned short ldsA[2][4096];     // [buf][128*32] swizzled
    __shared__ unsigned short ldsB[2][4096];
    int bid = blockIdx.x;
    int xcd = bid & 7;
    int q   = bid >> 3;                          // 0..47
    int MI  = xcd * 3 + (q % 3);                 // 0..23
    int NI  = q / 3;                             // 0..15
    int i    = threadIdx.x;
    int w = i >> 6, lane = i & 63;
    int lm = lane & 15, lq = lane >> 4;
    int wr = w >> 1, wc = w & 1;

    int mm0 = ((i >> 2) & 7) ^ ((i >> 4) & 1);   // writer inverse swizzle
    int li  = i ^ mm0;
    const unsigned short* gA = Xemb + (size_t)(MI * 128 + (li >> 2)) * 512 + (li & 3) * 8;
    const unsigned short* gB = Wih  + (size_t)(NI * 128 + (li >> 2)) * 512 + (li & 3) * 8;
    unsigned short* lA = &ldsA[0][0] + i * 8;
    unsigned short* lB = &ldsB[0][0] + i * 8;

    auto stage = [&](int buf, int ks) {
        int go = ks * 32;
        gl16(gA + go,            lA + buf * 4096);
        gl16(gA + go + 64 * 512, lA + buf * 4096 + 2048);
        gl16(gB + go,            lB + buf * 4096);
        gl16(gB + go + 64 * 512, lB + buf * 4096 + 2048);
    };

    f32x4 acc[4][4] = {};
    stage(0, 0);
    for (int ksi = 0; ksi < 16; ksi++) {
        int cur = ksi & 1;
        if (ksi < 15) stage(cur ^ 1, ksi + 1);
        __syncthreads();
        bf16x8 af[4], bfr[4];
        #pragma unroll
        for (int mi = 0; mi < 4; mi++)
            af[mi] = *(const bf16x8*)&ldsA[cur][swz16(wr * 64 + mi * 16 + lm, lq)];
        #pragma unroll
        for (int ni = 0; ni < 4; ni++)
            bfr[ni] = *(const bf16x8*)&ldsB[cur][swz16(wc * 64 + ni * 16 + lm, lq)];
        #pragma unroll
        for (int mi = 0; mi < 4; mi++)
            #pragma unroll
            for (int ni = 0; ni < 4; ni++)
                acc[mi][ni] = MFMA_16x16x32_BF16(af[mi], bfr[ni], acc[mi][ni]);
        __syncthreads();
    }

    float bias[4];
    #pragma unroll
    for (int ni = 0; ni < 4; ni++) {
        int n = NI * 128 + wc * 64 + ni * 16 + lm;
        bias[ni] = bih[n] + bhh[n];
    }
    #pragma unroll
    for (int mi = 0; mi < 4; mi++) {
        #pragma unroll
        for (int r = 0; r < 4; r++) {
            int m = MI * 128 + wr * 64 + mi * 16 + lq * 4 + r;
            #pragma unroll
            for (int ni = 0; ni < 4; ni++) {
                int n = NI * 128 + wc * 64 + ni * 16 + lm;
                P[(size_t)m * G4 + n] = acc[mi][ni][r] + bias[ni];
            }
        }
    }
}

// ---------------------------------------------------------------------------
// Per-step fused kernel. K-split x8: 256 blocks x 8 waves (2 waves/SIMD for
// latency hiding; R4's 4-wave version was 1/SIMD). Wave w owns K-slice
// [w*64,+64) of all four gate tiles; LDS reduce; waves 0..3 do the cell for
// row r==w. P/c prefetch issued before the MFMA chain.
// ---------------------------------------------------------------------------
__global__ __launch_bounds__(512) void k_step(const float* __restrict__ Pt,     // P + t*128*2048
                                              const unsigned short* __restrict__ h_in,
                                              const unsigned short* __restrict__ Whh,
                                              float* __restrict__ c,
                                              unsigned short* __restrict__ h_out,
                                              unsigned short* __restrict__ Hall_t,
                                              int t) {
    __shared__ float part[16][8][64];            // [g*4+r][wave][lane] = 32 KB
    int w    = threadIdx.x >> 6;                 // 0..7 (K-slice; w<4 also cell row)
    int lane = threadIdx.x & 63;
    int lm = lane & 15, lq = lane >> 4;
    int MI = blockIdx.x >> 5;                    // 0..7  (batch rows MI*16..+16)
    int HG = blockIdx.x & 31;                    // 0..31 (h-cols HG*16..+16)
    int hcol = HG * 16 + lm;
    int ks = w * 64;
    int brow = MI * 16 + lq * 4 + w;             // cell row (valid for w<4)

    // prefetch P (xW+bias) + c_prev for the cell phase (waves 0..3 only)
    float pv0 = 0.f, pv1 = 0.f, pv2 = 0.f, pv3 = 0.f, cp = 0.f;
    if (w < 4) {
        const float* Pr = Pt + (size_t)brow * G4;
        pv0 = Pr[0 * 512 + hcol];
        pv1 = Pr[1 * 512 + hcol];
        pv2 = Pr[2 * 512 + hcol];
        pv3 = Pr[3 * 512 + hcol];
        if (t != 0) cp = c[brow * H_ + hcol];
    }

    // K-slice GEMM (2 k-chunks of 32)
    const short* A  = (const short*)h_in + (long)(MI * 16 + lm) * H_ + ks;
    const short* B0 = (const short*)Whh + (long)(0 * 512 + hcol) * H_ + ks;
    const short* B1 = (const short*)Whh + (long)(1 * 512 + hcol) * H_ + ks;
    const short* B2 = (const short*)Whh + (long)(2 * 512 + hcol) * H_ + ks;
    const short* B3 = (const short*)Whh + (long)(3 * 512 + hcol) * H_ + ks;

    f32x4 acc[4] = {};
    #pragma unroll
    for (int kk = 0; kk < 2; kk++) {
        int ko = kk * 32 + lq * 8;
        bf16x8 a = *(const bf16x8*)(A + ko);
        acc[0] = MFMA_16x16x32_BF16(a, *(const bf16x8*)(B0 + ko), acc[0]);
        acc[1] = MFMA_16x16x32_BF16(a, *(const bf16x8*)(B1 + ko), acc[1]);
        acc[2] = MFMA_16x16x32_BF16(a, *(const bf16x8*)(B2 + ko), acc[2]);
        acc[3] = MFMA_16x16x32_BF16(a, *(const bf16x8*)(B3 + ko), acc[3]);
    }

    #pragma unroll
    for (int g = 0; g < 4; g++)
        #pragma unroll
        for (int r = 0; r < 4; r++)
            part[g * 4 + r][w][lane] = acc[g][r];
    __syncthreads();

    if (w < 4) {
        // reduce 8 K-partials (w'=0..7 ascending) + cell for row r==w
        float gi = pv0, gf = pv1, gg = pv2, go = pv3;
        #pragma unroll
        for (int wp = 0; wp < 8; wp++) gi += part[0 * 4 + w][wp][lane];
        #pragma unroll
        for (int wp = 0; wp < 8; wp++) gf += part[1 * 4 + w][wp][lane];
        #pragma unroll
        for (int wp = 0; wp < 8; wp++) gg += part[2 * 4 + w][wp][lane];
        #pragma unroll
        for (int wp = 0; wp < 8; wp++) go += part[3 * 4 + w][wp][lane];
        float si = 1.f / (1.f + expf(-gi));
        float sf = 1.f / (1.f + expf(-gf));
        float so = 1.f / (1.f + expf(-go));
        float cn = sf * cp + si * tanhf(gg);
        float hn = so * tanhf(cn);
        c[brow * H_ + hcol] = cn;
        unsigned short hb = f2bf(hn);
        h_out[brow * H_ + hcol] = hb;
        Hall_t[brow * H_ + hcol] = hb;
    }
}

// ---------------------------------------------------------------------------
// Logits: Hall[3072,512](bf16) @ Wout_bf^T + b_out -> fp32 out[b][t+1][v].
// 128x128 LDS tiles, double-buffered global_load_lds, bank-conflict swizzle
// (both-sides: pre-swizzled global source + swizzled ds_read).
// Grid = 8 * (3*79) = 1896; XCD owns 3 M-tiles, streams 79 B-panels.
// ---------------------------------------------------------------------------
__global__ __launch_bounds__(256) void k_logits(const unsigned short* __restrict__ Hall,
                                                const unsigned short* __restrict__ Wout,
                                                const float* __restrict__ bout,
                                                float* __restrict__ out) {
    __shared__ unsigned short ldsA[2][4096];     // [buf][128*32] swizzled
    __shared__ unsigned short ldsB[2][4096];
    int bid = blockIdx.x;
    int xcd = bid & 7;
    int q   = bid >> 3;                          // 0..236
    int MI  = xcd * 3 + (q % 3);                 // 0..23 (== timestep t)
    int NI  = q / 3;                             // 0..78
    int i    = threadIdx.x;
    int w = i >> 6, lane = i & 63;
    int lm = lane & 15, lq = lane >> 4;
    int wr = w >> 1, wc = w & 1;

    int mm0 = ((i >> 2) & 7) ^ ((i >> 4) & 1);   // writer inverse swizzle
    int li  = i ^ mm0;
    const unsigned short* gA = Hall + (size_t)(MI * 128 + (li >> 2)) * 512 + (li & 3) * 8;
    const unsigned short* gB = Wout + (size_t)(NI * 128 + (li >> 2)) * 512 + (li & 3) * 8;
    unsigned short* lA = &ldsA[0][0] + i * 8;
    unsigned short* lB = &ldsB[0][0] + i * 8;

    auto stage = [&](int buf, int ks) {
        int go = ks * 32;
        gl16(gA + go,            lA + buf * 4096);
        gl16(gA + go + 64 * 512, lA + buf * 4096 + 2048);
        gl16(gB + go,            lB + buf * 4096);
        gl16(gB + go + 64 * 512, lB + buf * 4096 + 2048);
    };

    f32x4 acc[4][4] = {};
    stage(0, 0);
    for (int ksi = 0; ksi < 16; ksi++) {
        int cur = ksi & 1;
        if (ksi < 15) stage(cur ^ 1, ksi + 1);
        __syncthreads();                         // staging of cur complete
        bf16x8 af[4], bfr[4];
        #pragma unroll
        for (int mi = 0; mi < 4; mi++)
            af[mi] = *(const bf16x8*)&ldsA[cur][swz16(wr * 64 + mi * 16 + lm, lq)];
        #pragma unroll
        for (int ni = 0; ni < 4; ni++)
            bfr[ni] = *(const bf16x8*)&ldsB[cur][swz16(wc * 64 + ni * 16 + lm, lq)];
        #pragma unroll
        for (int mi = 0; mi < 4; mi++)
            #pragma unroll
            for (int ni = 0; ni < 4; ni++)
                acc[mi][ni] = MFMA_16x16x32_BF16(af[mi], bfr[ni], acc[mi][ni]);
        __syncthreads();                         // done reading cur
    }

    // epilogue: rows of this M-tile are exactly (t = MI, b = 0..127)
    #pragma unroll
    for (int mi = 0; mi < 4; mi++) {
        #pragma unroll
        for (int r = 0; r < 4; r++) {
            int b = wr * 64 + mi * 16 + lq * 4 + r;
            float* orow = out + ((size_t)b * TP1 + MI + 1) * V_;
            #pragma unroll
            for (int ni = 0; ni < 4; ni++) {
                int n = NI * 128 + wc * 64 + ni * 16 + lm;
                if (n < V_) orow[n] = acc[mi][ni][r] + bout[n];
            }
        }
    }
}

// ---------------------------------------------------------------------------
extern "C" void kernel_launch(void* const* d_in, const int* in_sizes, int n_in,
                              void* d_out, int out_size, void* d_ws, size_t ws_size,
                              hipStream_t stream) {
    const float* images   = (const float*)d_in[0];
    const int*   captions = (const int*)d_in[1];
    const int*   cap_len  = (const int*)d_in[2];
    const float* Wemb     = (const float*)d_in[3];
    const float* Wih      = (const float*)d_in[4];
    const float* Whh      = (const float*)d_in[5];
    const float* bih      = (const float*)d_in[6];
    const float* bhh      = (const float*)d_in[7];
    const float* Wout     = (const float*)d_in[8];
    const float* bout     = (const float*)d_in[9];
    float* out = (float*)d_out;

    // workspace layout (all sizes multiples of 256B)
    char* ws = (char*)d_ws;
    unsigned short* Wih_bf  = (unsigned short*)(ws);              //  2,097,152
    unsigned short* Whh_bf  = (unsigned short*)(ws + 2097152);    //  2,097,152
    unsigned short* Wout_bf = (unsigned short*)(ws + 4194304);    // 10,354,688 (VP=10112 rows)
    unsigned short* Xemb    = (unsigned short*)(ws + 14548992);   //  3,145,728
    unsigned short* Hall    = (unsigned short*)(ws + 17694720);   //  3,145,728
    unsigned short* h0      = (unsigned short*)(ws + 20840448);   //    131,072
    unsigned short* h1      = (unsigned short*)(ws + 20971520);   //    131,072
    float*          cbuf    = (float*)(ws + 21102592);            //    262,144
    // P: 3072 x 2048 fp32 = 25,165,824. Prefer workspace; fall back to d_out
    // as scratch (safe: k_start + k_logits together rewrite every out byte
    // after the recurrence consumed P).
    constexpr size_t P_OFF   = 21364736;
    constexpr size_t WS_NEED = P_OFF + 25165824;   // 46,530,560
    float* P = (ws_size >= WS_NEED) ? (float*)(ws + P_OFF) : (float*)d_out;

    // staging: all fp32->bf16 in one launch + embedding gather
    k_cvt_all<<<7112, 256, 0, stream>>>(Wih, Whh, Wout, images,
                                        Wih_bf, Whh_bf, Wout_bf, h0);
    k_embed<<<1536, 256, 0, stream>>>(Wemb, captions, Xemb);

    // hoisted input GEMM: P = Xemb @ Wih^T + (bih + bhh)
    k_pregemm<<<384, 256, 0, stream>>>(Xemb, Wih_bf, bih, bhh, P);

    // serial recurrence: one launch per step (launch = cheap grid barrier)
    for (int t = 0; t < T_; t++) {
        const unsigned short* hin  = (t & 1) ? h1 : h0;
        unsigned short*       hout = (t & 1) ? h0 : h1;
        k_step<<<256, 512, 0, stream>>>(P + (long)t * B_ * G4, hin, Whh_bf,
                                        cbuf, hout, Hall + (long)t * B_ * H_, t);
    }

    // t=0 one-hot row + length tail
    k_start<<<1250, 256, 0, stream>>>(out, cap_len);

    // logits, LDS-staged 128x128 tiles (swizzled)
    k_logits<<<1896, 256, 0, stream>>>(Hall, Wout_bf, bout, out);
}